// Round 1
// baseline (641.956 us; speedup 1.0000x reference)
//
#include <hip/hip_runtime.h>

#define T_N 1024
#define H_N 128
#define CH   64
#define NCH (T_N / CH)     // 16
#define WPAD 136           // shorts per row of bf16 [n][k] weight tiles (272B rows: 2-way banks only)
#define TPAD 68            // floats per row of pT [h][t] (272B rows: 16B aligned, 2-way banks only)

typedef __attribute__((ext_vector_type(8))) short bf16x8;
typedef __attribute__((ext_vector_type(4))) float f32x4;

__device__ __forceinline__ short f2bf_rne(float f) {
    union { float f; unsigned int i; } v; v.f = f;
    unsigned int r = v.i + 0x7FFFu + ((v.i >> 16) & 1u);
    return (short)(r >> 16);
}
__device__ __forceinline__ float tanh_fast(float x) {
    return 1.0f - 2.0f / (__expf(2.0f * x) + 1.0f);
}

// One block per batch row, 2 waves.
// wave0: barrier-free recurrence. Full 128-wide matvec per step: 8 col-tiles x 4
//        chained mfma_16x16x32_bf16 with A = state broadcast (verified frag layout).
//        State weights in 128 VGPRs; state = 256B LDS; tanh split across q via
//        cndmask selects. NO __syncthreads in the step loop.
// wave1: computes chunk c+1's input projection into pT[other] while wave0 steps
//        through chunk c. One barrier per 64 steps (was: one per step).
__global__ __launch_bounds__(128, 1) void k_fused(const float* __restrict__ x,
                                                  const float* __restrict__ w,
                                                  const float* __restrict__ wst,
                                                  const float* __restrict__ bias,
                                                  float* __restrict__ out) {
    __shared__ __align__(16) short wT[H_N * WPAD];     // input-proj w, bf16 [n][k]
    __shared__ __align__(16) float pT[2][H_N * TPAD];  // proj chunk [h][t] dbuf; wsT staging at startup
    __shared__ __align__(16) short sst[H_N];           // state, bf16, natural order

    const int tid  = threadIdx.x;
    const int wv   = tid >> 6;
    const int lane = tid & 63;
    const int l = lane & 15;
    const int q = lane >> 4;
    const int r = blockIdx.x;
    const float* xrow = x + (size_t)r * T_N * H_N;
    const f32x4 zero4 = (f32x4){0.f, 0.f, 0.f, 0.f};

    // ---- stage wst -> bf16 [n][k] through pT[0]'s memory (exactly fits) ----
    short* wsTs = reinterpret_cast<short*>(&pT[0][0]);
    for (int e = tid * 4; e < H_N * H_N; e += 512) {
        int k = e >> 7, n = e & 127;
        float4 a4 = *reinterpret_cast<const float4*>(wst + e);
        wsTs[(n + 0) * WPAD + k] = f2bf_rne(a4.x);
        wsTs[(n + 1) * WPAD + k] = f2bf_rne(a4.y);
        wsTs[(n + 2) * WPAD + k] = f2bf_rne(a4.z);
        wsTs[(n + 3) * WPAD + k] = f2bf_rne(a4.w);
    }
    // ---- stage w -> bf16 [n][k] LDS ----
    for (int e = tid * 4; e < H_N * H_N; e += 512) {
        int k = e >> 7, n = e & 127;
        float4 a4 = *reinterpret_cast<const float4*>(w + e);
        wT[(n + 0) * WPAD + k] = f2bf_rne(a4.x);
        wT[(n + 1) * WPAD + k] = f2bf_rne(a4.y);
        wT[(n + 2) * WPAD + k] = f2bf_rne(a4.z);
        wT[(n + 3) * WPAD + k] = f2bf_rne(a4.w);
    }

    float bv[8];
    #pragma unroll
    for (int nt = 0; nt < 8; ++nt) bv[nt] = bias[nt * 16 + l];

    __syncthreads();

    // ---- chunk proj GEMM (wave1): proj rows [cc*64 .. +63] -> buf [h][t] f32 ----
    auto do_chunk = [&](int cc, float* buf) {
        const float* xc = xrow + (size_t)cc * CH * H_N + (size_t)l * H_N + q * 8;
        #pragma unroll 1
        for (int tile = 0; tile < 4; ++tile) {
            const float* xp = xc + (size_t)tile * 16 * H_N;
            float4 u[8];
            #pragma unroll
            for (int ks = 0; ks < 4; ++ks) {
                u[2 * ks]     = *reinterpret_cast<const float4*>(xp + ks * 32);
                u[2 * ks + 1] = *reinterpret_cast<const float4*>(xp + ks * 32 + 4);
            }
            bf16x8 ax[4];
            #pragma unroll
            for (int ks = 0; ks < 4; ++ks) {
                float4 u0 = u[2 * ks], u1 = u[2 * ks + 1];
                bf16x8 f;
                f[0] = f2bf_rne(u0.x); f[1] = f2bf_rne(u0.y);
                f[2] = f2bf_rne(u0.z); f[3] = f2bf_rne(u0.w);
                f[4] = f2bf_rne(u1.x); f[5] = f2bf_rne(u1.y);
                f[6] = f2bf_rne(u1.z); f[7] = f2bf_rne(u1.w);
                ax[ks] = f;
            }
            #pragma unroll
            for (int nt = 0; nt < 8; ++nt) {
                f32x4 acc;
                #pragma unroll
                for (int ks = 0; ks < 4; ++ks) {
                    bf16x8 bw = *reinterpret_cast<const bf16x8*>(
                        &wT[(nt * 16 + l) * WPAD + ks * 32 + q * 8]);
                    acc = __builtin_amdgcn_mfma_f32_16x16x32_bf16(
                        ax[ks], bw, ks == 0 ? zero4 : acc, 0, 0, 0);
                }
                f32x4 o = (f32x4){acc[0] + bv[nt], acc[1] + bv[nt],
                                  acc[2] + bv[nt], acc[3] + bv[nt]};
                *reinterpret_cast<f32x4*>(
                    &buf[(nt * 16 + l) * TPAD + tile * 16 + 4 * q]) = o;
            }
        }
    };

    bf16x8 wf[8][4];   // state-weight B-frags, wave0 only (128 VGPRs, loaded once)
    if (wv == 0) {
        #pragma unroll
        for (int nt = 0; nt < 8; ++nt)
            #pragma unroll
            for (int ks = 0; ks < 4; ++ks)
                wf[nt][ks] = *reinterpret_cast<const bf16x8*>(
                    &wsTs[(16 * nt + l) * WPAD + ks * 32 + q * 8]);
    } else {
        do_chunk(0, &pT[1][0]);   // chunk 0 -> pT[1] (pT[0] still holds wsT)
    }
    __syncthreads();

    float y0 = 0.f, y1 = 0.f;
    const int row0 = (32 * q + l) * TPAD;
    const int row1 = (32 * q + 16 + l) * TPAD;

    #pragma unroll 1
    for (int c = 0; c < NCH; ++c) {
        if (wv == 0) {
            // chunk cc lives in pT[(cc+1)&1]
            float* pc = &pT[(c + 1) & 1][0];
            int ts = 0;
            if (c == 0) {
                // state0 = tanh(proj[0]) — no recurrent term
                sst[lane]      = f2bf_rne(tanh_fast(pc[lane * TPAD]));
                sst[64 + lane] = f2bf_rne(tanh_fast(pc[(64 + lane) * TPAD]));
                ts = 1;
            }
            float p0 = pc[row0 + ts];
            float p1 = pc[row1 + ts];
            #pragma unroll 1
            for (int t = ts; t < CH; ++t) {
                // A-frags: state broadcast to all 16 rows (4 distinct 16B addrs -> free)
                bf16x8 a[4];
                #pragma unroll
                for (int ks = 0; ks < 4; ++ks)
                    a[ks] = *reinterpret_cast<const bf16x8*>(&sst[ks * 32 + q * 8]);

                // 8 independent chains x 4 chained MFMAs: full 128-wide matvec
                f32x4 acc[8];
                #pragma unroll
                for (int nt = 0; nt < 8; ++nt) {
                    #pragma unroll
                    for (int ks = 0; ks < 4; ++ks)
                        acc[nt] = __builtin_amdgcn_mfma_f32_16x16x32_bf16(
                            a[ks], wf[nt][ks], ks == 0 ? zero4 : acc[nt], 0, 0, 0);
                }

                int tn = (t + 1 < CH) ? t + 1 : t;
                float np0 = pc[row0 + tn];
                float np1 = pc[row1 + tn];

                // lane (q,l) owns cols 32q+l and 32q+16+l -> tiles 2q, 2q+1
                float v0 = (q == 0) ? acc[0][0] : (q == 1) ? acc[2][0]
                         : (q == 2) ? acc[4][0] : acc[6][0];
                float v1 = (q == 0) ? acc[1][0] : (q == 1) ? acc[3][0]
                         : (q == 2) ? acc[5][0] : acc[7][0];
                y0 = tanh_fast(p0 + v0);
                y1 = tanh_fast(p1 + v1);
                sst[32 * q + l]      = f2bf_rne(y0);
                sst[32 * q + 16 + l] = f2bf_rne(y1);
                p0 = np0; p1 = np1;
                // no barrier: single-wave recurrence, lgkm ordering only
            }
        } else if (c + 1 < NCH) {
            do_chunk(c + 1, &pT[c & 1][0]);
        }
        __syncthreads();   // chunk handoff (1 barrier / 64 steps)
    }

    if (wv == 0) {
        out[r * H_N + 32 * q + l]      = y0;
        out[r * H_N + 32 * q + 16 + l] = y1;
    }
}

extern "C" void kernel_launch(void* const* d_in, const int* in_sizes, int n_in,
                              void* d_out, int out_size, void* d_ws, size_t ws_size,
                              hipStream_t stream) {
    const float* x    = (const float*)d_in[0];  // [B][T][D] fp32
    const float* w    = (const float*)d_in[1];  // [D][H]    fp32
    const float* wst  = (const float*)d_in[2];  // [H][H]    fp32
    const float* bias = (const float*)d_in[3];  // [H]       fp32
    float* out = (float*)d_out;                 // [B][H]    fp32

    k_fused<<<256, 128, 0, stream>>>(x, w, wst, bias, out);
}

// Round 2
// 640.495 us; speedup vs baseline: 1.0023x; 1.0023x over previous
//
#include <hip/hip_runtime.h>

#define T_N 1024
#define H_N 128
#define CH   64
#define NCH (T_N / CH)     // 16
#define WPAD 136           // shorts per row of bf16 [n][k] weight tiles (272B rows: 2-way banks only)
#define TPAD 68            // floats per row of pT [h][t] (272B rows: 16B aligned, 2-way banks only)

typedef __attribute__((ext_vector_type(8))) short bf16x8;
typedef __attribute__((ext_vector_type(4))) float f32x4;

__device__ __forceinline__ short f2bf_rne(float f) {
    union { float f; unsigned int i; } v; v.f = f;
    unsigned int r = v.i + 0x7FFFu + ((v.i >> 16) & 1u);
    return (short)(r >> 16);
}
__device__ __forceinline__ float tanh_fast(float x) {
    return 1.0f - 2.0f / (__expf(2.0f * x) + 1.0f);
}

// One block per batch row, 2 waves.
// wave0: barrier-free recurrence, full 128-wide matvec per step.
//   MFMA nest is ks-OUTER / nt-INNER: consecutive MFMAs are 8 independent
//   chains, so each chain's next link issues ~40cyc after its predecessor
//   (= dependent-MFMA latency) -> no issue stalls. sched_barrier(0) between
//   ks-groups stops LLVM from re-serializing into depth-4 chains (round-1
//   regression: chain-serial order cost ~780 stall cyc/step).
// wave1: computes chunk c+1's input projection while wave0 steps chunk c.
//   One barrier per 64 steps.
__global__ __launch_bounds__(128, 1) void k_fused(const float* __restrict__ x,
                                                  const float* __restrict__ w,
                                                  const float* __restrict__ wst,
                                                  const float* __restrict__ bias,
                                                  float* __restrict__ out) {
    __shared__ __align__(16) short wT[H_N * WPAD];     // input-proj w, bf16 [n][k]
    __shared__ __align__(16) float pT[2][H_N * TPAD];  // proj chunk [h][t] dbuf; wsT staging at startup
    __shared__ __align__(16) short sst[H_N];           // state, bf16, natural order

    const int tid  = threadIdx.x;
    const int wv   = tid >> 6;
    const int lane = tid & 63;
    const int l = lane & 15;
    const int q = lane >> 4;
    const int r = blockIdx.x;
    const float* xrow = x + (size_t)r * T_N * H_N;
    const f32x4 zero4 = (f32x4){0.f, 0.f, 0.f, 0.f};

    // ---- stage wst -> bf16 [n][k] through pT[0]'s memory (exactly fits) ----
    short* wsTs = reinterpret_cast<short*>(&pT[0][0]);
    for (int e = tid * 4; e < H_N * H_N; e += 512) {
        int k = e >> 7, n = e & 127;
        float4 a4 = *reinterpret_cast<const float4*>(wst + e);
        wsTs[(n + 0) * WPAD + k] = f2bf_rne(a4.x);
        wsTs[(n + 1) * WPAD + k] = f2bf_rne(a4.y);
        wsTs[(n + 2) * WPAD + k] = f2bf_rne(a4.z);
        wsTs[(n + 3) * WPAD + k] = f2bf_rne(a4.w);
    }
    // ---- stage w -> bf16 [n][k] LDS ----
    for (int e = tid * 4; e < H_N * H_N; e += 512) {
        int k = e >> 7, n = e & 127;
        float4 a4 = *reinterpret_cast<const float4*>(w + e);
        wT[(n + 0) * WPAD + k] = f2bf_rne(a4.x);
        wT[(n + 1) * WPAD + k] = f2bf_rne(a4.y);
        wT[(n + 2) * WPAD + k] = f2bf_rne(a4.z);
        wT[(n + 3) * WPAD + k] = f2bf_rne(a4.w);
    }

    float bv[8];
    #pragma unroll
    for (int nt = 0; nt < 8; ++nt) bv[nt] = bias[nt * 16 + l];

    __syncthreads();

    // ---- chunk proj GEMM (wave1): proj rows [cc*64 .. +63] -> buf [h][t] f32 ----
    auto do_chunk = [&](int cc, float* buf) {
        const float* xc = xrow + (size_t)cc * CH * H_N + (size_t)l * H_N + q * 8;
        #pragma unroll 1
        for (int tile = 0; tile < 4; ++tile) {
            const float* xp = xc + (size_t)tile * 16 * H_N;
            float4 u[8];
            #pragma unroll
            for (int ks = 0; ks < 4; ++ks) {
                u[2 * ks]     = *reinterpret_cast<const float4*>(xp + ks * 32);
                u[2 * ks + 1] = *reinterpret_cast<const float4*>(xp + ks * 32 + 4);
            }
            bf16x8 ax[4];
            #pragma unroll
            for (int ks = 0; ks < 4; ++ks) {
                float4 u0 = u[2 * ks], u1 = u[2 * ks + 1];
                bf16x8 f;
                f[0] = f2bf_rne(u0.x); f[1] = f2bf_rne(u0.y);
                f[2] = f2bf_rne(u0.z); f[3] = f2bf_rne(u0.w);
                f[4] = f2bf_rne(u1.x); f[5] = f2bf_rne(u1.y);
                f[6] = f2bf_rne(u1.z); f[7] = f2bf_rne(u1.w);
                ax[ks] = f;
            }
            // latency fully hidden behind wave0's 64 steps -> chain order is fine here
            #pragma unroll
            for (int nt = 0; nt < 8; ++nt) {
                f32x4 acc;
                #pragma unroll
                for (int ks = 0; ks < 4; ++ks) {
                    bf16x8 bw = *reinterpret_cast<const bf16x8*>(
                        &wT[(nt * 16 + l) * WPAD + ks * 32 + q * 8]);
                    acc = __builtin_amdgcn_mfma_f32_16x16x32_bf16(
                        ax[ks], bw, ks == 0 ? zero4 : acc, 0, 0, 0);
                }
                f32x4 o = (f32x4){acc[0] + bv[nt], acc[1] + bv[nt],
                                  acc[2] + bv[nt], acc[3] + bv[nt]};
                *reinterpret_cast<f32x4*>(
                    &buf[(nt * 16 + l) * TPAD + tile * 16 + 4 * q]) = o;
            }
        }
    };

    bf16x8 wf[8][4];   // state-weight B-frags, wave0 only (128 VGPRs, loaded once)
    if (wv == 0) {
        #pragma unroll
        for (int nt = 0; nt < 8; ++nt)
            #pragma unroll
            for (int ks = 0; ks < 4; ++ks)
                wf[nt][ks] = *reinterpret_cast<const bf16x8*>(
                    &wsTs[(16 * nt + l) * WPAD + ks * 32 + q * 8]);
    } else {
        do_chunk(0, &pT[1][0]);   // chunk 0 -> pT[1] (pT[0] still holds wsT)
    }
    __syncthreads();

    float y0 = 0.f, y1 = 0.f;
    const int row0 = (32 * q + l) * TPAD;
    const int row1 = (32 * q + 16 + l) * TPAD;

    #pragma unroll 1
    for (int c = 0; c < NCH; ++c) {
        if (wv == 0) {
            // chunk cc lives in pT[(cc+1)&1]
            float* pc = &pT[(c + 1) & 1][0];
            int ts = 0;
            if (c == 0) {
                // state0 = tanh(proj[0]) — no recurrent term
                sst[lane]      = f2bf_rne(tanh_fast(pc[lane * TPAD]));
                sst[64 + lane] = f2bf_rne(tanh_fast(pc[(64 + lane) * TPAD]));
                ts = 1;
            }
            float p0 = pc[row0 + ts];
            float p1 = pc[row1 + ts];
            #pragma unroll 1
            for (int t = ts; t < CH; ++t) {
                // A-frags: state broadcast (4 distinct 16B addrs -> conflict-free).
                // Issue all 4 first; ks0 only needs a[0] (fine-grained lgkmcnt).
                bf16x8 a[4];
                #pragma unroll
                for (int ks = 0; ks < 4; ++ks)
                    a[ks] = *reinterpret_cast<const bf16x8*>(&sst[ks * 32 + q * 8]);

                int tn = (t + 1 < CH) ? t + 1 : t;
                float np0 = pc[row0 + tn];
                float np1 = pc[row1 + tn];

                // ks-OUTER: 8 independent chains interleaved; sched_barrier(0)
                // between groups forbids re-serialization into depth-4 chains.
                f32x4 acc[8];
                #pragma unroll
                for (int nt = 0; nt < 8; ++nt)
                    acc[nt] = __builtin_amdgcn_mfma_f32_16x16x32_bf16(
                        a[0], wf[nt][0], zero4, 0, 0, 0);
                __builtin_amdgcn_sched_barrier(0);
                #pragma unroll
                for (int nt = 0; nt < 8; ++nt)
                    acc[nt] = __builtin_amdgcn_mfma_f32_16x16x32_bf16(
                        a[1], wf[nt][1], acc[nt], 0, 0, 0);
                __builtin_amdgcn_sched_barrier(0);
                #pragma unroll
                for (int nt = 0; nt < 8; ++nt)
                    acc[nt] = __builtin_amdgcn_mfma_f32_16x16x32_bf16(
                        a[2], wf[nt][2], acc[nt], 0, 0, 0);
                __builtin_amdgcn_sched_barrier(0);
                #pragma unroll
                for (int nt = 0; nt < 8; ++nt)
                    acc[nt] = __builtin_amdgcn_mfma_f32_16x16x32_bf16(
                        a[3], wf[nt][3], acc[nt], 0, 0, 0);

                // lane (q,l) owns cols 32q+l and 32q+16+l -> tiles 2q, 2q+1
                // (all q-groups hold identical D rows: broadcast A)
                float v0 = (q == 0) ? acc[0][0] : (q == 1) ? acc[2][0]
                         : (q == 2) ? acc[4][0] : acc[6][0];
                float v1 = (q == 0) ? acc[1][0] : (q == 1) ? acc[3][0]
                         : (q == 2) ? acc[5][0] : acc[7][0];
                y0 = tanh_fast(p0 + v0);
                y1 = tanh_fast(p1 + v1);
                sst[32 * q + l]      = f2bf_rne(y0);
                sst[32 * q + 16 + l] = f2bf_rne(y1);
                p0 = np0; p1 = np1;
                // no barrier: single-wave recurrence, DS ops in-order per wave
            }
        } else if (c + 1 < NCH) {
            do_chunk(c + 1, &pT[c & 1][0]);
        }
        __syncthreads();   // chunk handoff (1 barrier / 64 steps)
    }

    if (wv == 0) {
        out[r * H_N + 32 * q + l]      = y0;
        out[r * H_N + 32 * q + 16 + l] = y1;
    }
}

extern "C" void kernel_launch(void* const* d_in, const int* in_sizes, int n_in,
                              void* d_out, int out_size, void* d_ws, size_t ws_size,
                              hipStream_t stream) {
    const float* x    = (const float*)d_in[0];  // [B][T][D] fp32
    const float* w    = (const float*)d_in[1];  // [D][H]    fp32
    const float* wst  = (const float*)d_in[2];  // [H][H]    fp32
    const float* bias = (const float*)d_in[3];  // [H]       fp32
    float* out = (float*)d_out;                 // [B][H]    fp32

    k_fused<<<256, 128, 0, stream>>>(x, w, wst, bias, out);
}